// Round 6
// baseline (572.772 us; speedup 1.0000x reference)
//
#include <hip/hip_runtime.h>
#include <hip/hip_bf16.h>
#include <math.h>

#define NB   16
#define NTOK 577
#define CDIM 768
#define NH   12
#define HID  3072
#define RTOT (NB*NTOK)        // 9232
#define MT   ((RTOT+127)/128) // 73
#define RPAD (MT*128)         // 9344
#define BH   (NB*NH)          // 192
#define QT   40               // 640/16 fragment-tiles per (b,h)
#define KF_C (CDIM/32)        // 24  (Kf for 768-dim blobs)

typedef __attribute__((ext_vector_type(8))) short bf16x8;
typedef __attribute__((ext_vector_type(4))) float f32x4;
typedef unsigned short u16;

__device__ inline void load_lds16(const void* g, void* l) {
    __builtin_amdgcn_global_load_lds(
        (const __attribute__((address_space(1))) unsigned*)g,
        (__attribute__((address_space(3))) unsigned*)l, 16, 0, 0);
}

// fragment-blob address for element (m, c) of an [M][C] bf16 matrix packed in
// MFMA A-operand order: blob(mt, kf) is 512 u16, lane(fq*16+fr) holds 8 elems.
__device__ inline size_t blobA(int m, int c, int Kf) {
    return ((size_t)(m >> 4) * Kf + (c >> 5)) * 512 +
           (((c >> 3) & 3) * 16 + (m & 15)) * 8 + (c & 7);
}

// exp-based tanh gelu
__device__ inline float fast_gelu(float x) {
    float y = 0.7978845608f * (x + 0.044715f * x * x * x);
    float e = __expf(2.0f * y);
    float th = 1.0f - 2.0f / (e + 1.0f);
    return 0.5f * x * (1.0f + th);
}

// ---------------------------------------------------------------------------
// Weight fp32 [K][N] -> bf16 fragment blobs (B-operand: roles m->n, c->k).
// grid (N/256, K/8); thread: 8 strided reads, one coalesced 16B store.
// ---------------------------------------------------------------------------
__global__ __launch_bounds__(256) void wconvert_blob(
    const float* __restrict__ src, u16* __restrict__ dst, int K, int N)
{
    int n  = blockIdx.x * 256 + threadIdx.x;
    int kp = blockIdx.y;                     // k-chunk of 8
    ushort4 a, b;
    const float* s = src + (size_t)(kp * 8) * N + n;
    __hip_bfloat16 h0 = __float2bfloat16(s[0 * N]);
    __hip_bfloat16 h1 = __float2bfloat16(s[1 * N]);
    __hip_bfloat16 h2 = __float2bfloat16(s[2 * N]);
    __hip_bfloat16 h3 = __float2bfloat16(s[3 * N]);
    __hip_bfloat16 h4 = __float2bfloat16(s[4 * N]);
    __hip_bfloat16 h5 = __float2bfloat16(s[5 * N]);
    __hip_bfloat16 h6 = __float2bfloat16(s[6 * N]);
    __hip_bfloat16 h7 = __float2bfloat16(s[7 * N]);
    a = make_ushort4(*(u16*)&h0, *(u16*)&h1, *(u16*)&h2, *(u16*)&h3);
    b = make_ushort4(*(u16*)&h4, *(u16*)&h5, *(u16*)&h6, *(u16*)&h7);
    u16* d = dst + ((size_t)(n >> 4) * (K >> 5) + (kp >> 2)) * 512 +
             ((kp & 3) * 16 + (n & 15)) * 8;
    *(ushort4*)(d)     = a;
    *(ushort4*)(d + 4) = b;
}

// ---------------------------------------------------------------------------
// LayerNorm -> bf16 fragment blob (Kf = 24)
// ---------------------------------------------------------------------------
__global__ __launch_bounds__(256) void ln_kernel(
    const float* __restrict__ x, const float* __restrict__ g,
    const float* __restrict__ b, u16* __restrict__ out)
{
    int row = blockIdx.x;
    const float* xr = x + (size_t)row * CDIM;
    int t = threadIdx.x;
    float v0 = xr[t], v1 = xr[t + 256], v2 = xr[t + 512];
    float s  = v0 + v1 + v2;
    float s2 = v0*v0 + v1*v1 + v2*v2;
    #pragma unroll
    for (int off = 32; off; off >>= 1) {
        s  += __shfl_xor(s, off);
        s2 += __shfl_xor(s2, off);
    }
    __shared__ float red[10];
    int wave = t >> 6, lane = t & 63;
    if (lane == 0) { red[wave] = s; red[wave + 4] = s2; }
    __syncthreads();
    if (t == 0) {
        float ts  = red[0] + red[1] + red[2] + red[3];
        float ts2 = red[4] + red[5] + red[6] + red[7];
        float mu  = ts * (1.0f / CDIM);
        float var = ts2 * (1.0f / CDIM) - mu * mu;
        red[8] = mu;
        red[9] = rsqrtf(var + 1e-5f);
    }
    __syncthreads();
    float mu = red[8], rs = red[9];
    #pragma unroll
    for (int i = 0; i < 3; ++i) {
        int c = t + i * 256;
        float v = (i == 0 ? v0 : (i == 1 ? v1 : v2));
        __hip_bfloat16 hb = __float2bfloat16((v - mu) * rs * g[c] + b[c]);
        out[blobA(row, c, KF_C)] = *(u16*)&hb;
    }
}

// ---------------------------------------------------------------------------
// Barrier-free flatmm: out[M,Nc] = act(A @ B^T + bias) (+res)
// A, B in fragment-blob order. No LDS, no __syncthreads: per-wave pipelined
// global->VGPR fragment loads feed MFMA directly.
// flags: bit0=gelu, bit1=bf16 row-major out, bit2=bf16 blob out.
// ---------------------------------------------------------------------------
__global__ __launch_bounds__(256) void flat_gemm(
    const u16* __restrict__ Ab, const u16* __restrict__ Bb,
    const float* __restrict__ bias, const float* __restrict__ res,
    void* __restrict__ outv, int M, int Nc, int K, int flags)
{
    int t = threadIdx.x, lane = t & 63, wv = t >> 6;
    int fr = lane & 15, fq = lane >> 4;
    int Kf = K >> 5;
    int m0 = blockIdx.y * 128, n0 = blockIdx.x * 128;
    int wm = (wv >> 1) * 64, wn = (wv & 1) * 64;

    size_t tstr = (size_t)Kf * 512;
    const u16* Ap = Ab + (size_t)((m0 + wm) >> 4) * tstr + lane * 8;
    const u16* Bp = Bb + (size_t)((n0 + wn) >> 4) * tstr + lane * 8;

    f32x4 acc[4][4];
    #pragma unroll
    for (int i = 0; i < 4; ++i)
        #pragma unroll
        for (int j = 0; j < 4; ++j) acc[i][j] = (f32x4){0.f, 0.f, 0.f, 0.f};

    bf16x8 af[4], bf[4];
    #pragma unroll
    for (int tm = 0; tm < 4; ++tm) af[tm] = *(const bf16x8*)(Ap + tm * tstr);
    #pragma unroll
    for (int tn = 0; tn < 4; ++tn) bf[tn] = *(const bf16x8*)(Bp + tn * tstr);

    for (int kf = 0; kf < Kf; ++kf) {
        bf16x8 an[4], bn[4];
        if (kf + 1 < Kf) {
            size_t o = (size_t)(kf + 1) * 512;
            #pragma unroll
            for (int tm = 0; tm < 4; ++tm)
                an[tm] = *(const bf16x8*)(Ap + tm * tstr + o);
            #pragma unroll
            for (int tn = 0; tn < 4; ++tn)
                bn[tn] = *(const bf16x8*)(Bp + tn * tstr + o);
        }
        #pragma unroll
        for (int tm = 0; tm < 4; ++tm)
            #pragma unroll
            for (int tn = 0; tn < 4; ++tn)
                acc[tm][tn] = __builtin_amdgcn_mfma_f32_16x16x32_bf16(
                    af[tm], bf[tn], acc[tm][tn], 0, 0, 0);
        #pragma unroll
        for (int i = 0; i < 4; ++i) { af[i] = an[i]; bf[i] = bn[i]; }
    }

    float* outf = (float*)outv;
    __hip_bfloat16* outb = (__hip_bfloat16*)outv;
    u16* outblob = (u16*)outv;
    int gelu = flags & 1;
    int KfO = Nc >> 5;
    #pragma unroll
    for (int tm = 0; tm < 4; ++tm) {
        #pragma unroll
        for (int rg = 0; rg < 4; ++rg) {
            int gm = m0 + wm + tm * 16 + fq * 4 + rg;
            if (gm >= M) continue;
            #pragma unroll
            for (int tn = 0; tn < 4; ++tn) {
                int gn = n0 + wn + tn * 16 + fr;
                float v = acc[tm][tn][rg] + bias[gn];
                if (gelu) v = fast_gelu(v);
                if (res)  v += res[(size_t)gm * Nc + gn];
                if (flags & 4) {
                    __hip_bfloat16 hb = __float2bfloat16(v);
                    outblob[blobA(gm, gn, KfO)] = *(u16*)&hb;
                } else if (flags & 2) {
                    outb[(size_t)gm * Nc + gn] = __float2bfloat16(v);
                } else {
                    outf[(size_t)gm * Nc + gn] = v;
                }
            }
        }
    }
}

// ---------------------------------------------------------------------------
// Repack qkv (bf16 row-major [RTOT][2304]) into attention blobs.
// ---------------------------------------------------------------------------
__global__ __launch_bounds__(256) void repack_qk(
    const u16* __restrict__ qkv, u16* __restrict__ Qp, u16* __restrict__ Kp)
{
    __shared__ u16 blob[1024];
    int mt = blockIdx.x, bh = blockIdx.y, sec = blockIdx.z;
    int b = bh / NH, h = bh % NH;
    int t = threadIdx.x;
    int r = t >> 4, d = (t & 15) * 4;
    int row = mt * 16 + r;
    ushort4 v = make_ushort4(0, 0, 0, 0);
    if (row < NTOK)
        v = *(const ushort4*)(qkv + (size_t)(b * NTOK + row) * 2304 + sec * 768 + h * 64 + d);
    int kf = d >> 5, fq = (d >> 3) & 3, jj = d & 7;
    u16* p = blob + kf * 512 + (fq * 16 + r) * 8 + jj;
    p[0] = v.x; p[1] = v.y; p[2] = v.z; p[3] = v.w;
    __syncthreads();
    u16* dst = (sec == 0 ? Qp : Kp) + (size_t)(bh * QT + mt) * 1024;
    *(ushort4*)(dst + t * 4) = *(const ushort4*)(blob + t * 4);
}

__global__ __launch_bounds__(256) void repack_v(
    const u16* __restrict__ qkv, u16* __restrict__ Vp)
{
    __shared__ u16 blob[4096];
    int jt = blockIdx.x, bh = blockIdx.y;
    int b = bh / NH, h = bh % NH;
    int t = threadIdx.x;
    int d = (t & 15) * 4;
    int dt = d >> 4;
    #pragma unroll
    for (int it = 0; it < 4; ++it) {
        int jr = (t >> 4) + it * 16;
        int row = jt * 64 + jr;
        ushort4 v = make_ushort4(0, 0, 0, 0);
        if (row < NTOK)
            v = *(const ushort4*)(qkv + (size_t)(b * NTOK + row) * 2304 + 1536 + h * 64 + d);
        int jf = jr >> 5, fq = (jr >> 3) & 3, jj = jr & 7;
        u16* p = blob + (dt * 2 + jf) * 512 + (fq * 16 + (d & 15)) * 8 + jj;
        p[0] = v.x; p[8] = v.y; p[16] = v.z; p[24] = v.w;
    }
    __syncthreads();
    #pragma unroll
    for (int dd = 0; dd < 4; ++dd) {
        size_t dstoff = ((size_t)(bh * 4 + dd) * 20 + jt * 2) * 512;
        *(ushort4*)(Vp + dstoff + t * 4) = *(const ushort4*)(blob + dd * 1024 + t * 4);
    }
}

// ---------------------------------------------------------------------------
// MFMA flash attention; output written in fragment-blob order (proj's A).
// ---------------------------------------------------------------------------
__global__ __launch_bounds__(256) void attn_mfma(
    const u16* __restrict__ Qp, const u16* __restrict__ Kp,
    const u16* __restrict__ Vp, u16* __restrict__ outp)
{
    __shared__ __align__(16) u16 Ks[4096];
    __shared__ __align__(16) u16 Vs[4096];
    __shared__ __align__(16) u16 Ps[4 * 16 * 72];

    int bh = blockIdx.y, qc = blockIdx.x;
    int b = bh / NH, h = bh % NH;
    int t = threadIdx.x, lane = t & 63, wv = t >> 6;
    int fr = lane & 15, fq = lane >> 4;

    int mt = qc * 4 + wv;
    const u16* qbase = Qp + (size_t)(bh * QT + mt) * 1024 + lane * 8;
    bf16x8 qf0 = *(const bf16x8*)(qbase);
    bf16x8 qf1 = *(const bf16x8*)(qbase + 512);

    const u16* kg = Kp + (size_t)bh * (QT * 1024) + wv * 1024 + lane * 8;
    const u16* vg = Vp + ((size_t)(bh * 4 + wv) * 20) * 512 + lane * 8;
    u16* lK  = Ks + wv * 1024;
    u16* lV  = Vs + wv * 1024;
    u16* psw = Ps + wv * (16 * 72);

    f32x4 o[4];
    float m_r[4], l_r[4];
    #pragma unroll
    for (int i = 0; i < 4; ++i) {
        o[i] = (f32x4){0.f, 0.f, 0.f, 0.f};
        m_r[i] = -1e30f; l_r[i] = 0.f;
    }

    for (int kt = 0; kt < 10; ++kt) {
        load_lds16(kg + kt * 4096,       lK);
        load_lds16(kg + kt * 4096 + 512, lK + 512);
        load_lds16(vg + kt * 1024,       lV);
        load_lds16(vg + kt * 1024 + 512, lV + 512);
        __syncthreads();

        f32x4 sc[4];
        #pragma unroll
        for (int nt = 0; nt < 4; ++nt) {
            sc[nt] = (f32x4){0.f, 0.f, 0.f, 0.f};
            bf16x8 kf0 = *(const bf16x8*)(Ks + (nt * 2 + 0) * 512 + lane * 8);
            bf16x8 kf1 = *(const bf16x8*)(Ks + (nt * 2 + 1) * 512 + lane * 8);
            sc[nt] = __builtin_amdgcn_mfma_f32_16x16x32_bf16(qf0, kf0, sc[nt], 0, 0, 0);
            sc[nt] = __builtin_amdgcn_mfma_f32_16x16x32_bf16(qf1, kf1, sc[nt], 0, 0, 0);
        }

        int j0 = kt * 64;
        float p[4][4], rm[4];
        #pragma unroll
        for (int rg = 0; rg < 4; ++rg) rm[rg] = -1e30f;
        #pragma unroll
        for (int nt = 0; nt < 4; ++nt) {
            bool valid = (j0 + nt * 16 + fr) < NTOK;
            #pragma unroll
            for (int rg = 0; rg < 4; ++rg) {
                float sv = valid ? sc[nt][rg] * 0.125f : -1e30f;
                p[nt][rg] = sv;
                rm[rg] = fmaxf(rm[rg], sv);
            }
        }
        #pragma unroll
        for (int rg = 0; rg < 4; ++rg) {
            #pragma unroll
            for (int off = 1; off < 16; off <<= 1)
                rm[rg] = fmaxf(rm[rg], __shfl_xor(rm[rg], off));
        }
        float alpha[4], rs[4];
        #pragma unroll
        for (int rg = 0; rg < 4; ++rg) {
            float mn = fmaxf(m_r[rg], rm[rg]);
            alpha[rg] = __expf(m_r[rg] - mn);
            m_r[rg] = mn;
            rs[rg] = 0.f;
        }
        #pragma unroll
        for (int nt = 0; nt < 4; ++nt)
            #pragma unroll
            for (int rg = 0; rg < 4; ++rg) {
                float pv = __expf(p[nt][rg] - m_r[rg]);
                p[nt][rg] = pv;
                rs[rg] += pv;
            }
        #pragma unroll
        for (int rg = 0; rg < 4; ++rg) {
            #pragma unroll
            for (int off = 1; off < 16; off <<= 1)
                rs[rg] += __shfl_xor(rs[rg], off);
            l_r[rg] = l_r[rg] * alpha[rg] + rs[rg];
        }

        #pragma unroll
        for (int nt = 0; nt < 4; ++nt)
            #pragma unroll
            for (int rg = 0; rg < 4; ++rg) {
                __hip_bfloat16 hb = __float2bfloat16(p[nt][rg]);
                psw[(fq * 4 + rg) * 72 + nt * 16 + fr] = *(u16*)&hb;
            }
        #pragma unroll
        for (int dt = 0; dt < 4; ++dt)
            #pragma unroll
            for (int rg = 0; rg < 4; ++rg)
                o[dt][rg] *= alpha[rg];

        bf16x8 pf0 = *(const bf16x8*)(psw + fr * 72 + fq * 8);
        bf16x8 pf1 = *(const bf16x8*)(psw + fr * 72 + 32 + fq * 8);
        #pragma unroll
        for (int dt = 0; dt < 4; ++dt) {
            bf16x8 bv0 = *(const bf16x8*)(Vs + (dt * 2 + 0) * 512 + lane * 8);
            bf16x8 bv1 = *(const bf16x8*)(Vs + (dt * 2 + 1) * 512 + lane * 8);
            o[dt] = __builtin_amdgcn_mfma_f32_16x16x32_bf16(pf0, bv0, o[dt], 0, 0, 0);
            o[dt] = __builtin_amdgcn_mfma_f32_16x16x32_bf16(pf1, bv1, o[dt], 0, 0, 0);
        }
        __syncthreads();
    }

    #pragma unroll
    for (int rg = 0; rg < 4; ++rg) {
        int row = qc * 64 + wv * 16 + fq * 4 + rg;
        if (row < NTOK) {
            float rl = 1.0f / l_r[rg];
            int grow = b * NTOK + row;
            #pragma unroll
            for (int dt = 0; dt < 4; ++dt) {
                __hip_bfloat16 hb = __float2bfloat16(o[dt][rg] * rl);
                outp[blobA(grow, h * 64 + dt * 16 + fr, KF_C)] = *(u16*)&hb;
            }
        }
    }
}

// ---------------------------------------------------------------------------
extern "C" void kernel_launch(void* const* d_in, const int* in_sizes, int n_in,
                              void* d_out, int out_size, void* d_ws, size_t ws_size,
                              hipStream_t stream)
{
    const float* x      = (const float*)d_in[0];
    const float* ln1_g  = (const float*)d_in[1];
    const float* ln1_b  = (const float*)d_in[2];
    const float* w_qkv  = (const float*)d_in[3];
    const float* b_qkv  = (const float*)d_in[4];
    const float* w_proj = (const float*)d_in[5];
    const float* b_proj = (const float*)d_in[6];
    const float* ln2_g  = (const float*)d_in[7];
    const float* ln2_b  = (const float*)d_in[8];
    const float* w_fc1  = (const float*)d_in[9];
    const float* b_fc1  = (const float*)d_in[10];
    const float* w_fc2  = (const float*)d_in[11];
    const float* b_fc2  = (const float*)d_in[12];
    float* out = (float*)d_out;

    char* w = (char*)d_ws;
    u16* Bqkv = (u16*)w; w += (size_t)3*CDIM*CDIM*2;
    u16* Bproj= (u16*)w; w += (size_t)CDIM*CDIM*2;
    u16* Bfc1 = (u16*)w; w += (size_t)HID*CDIM*2;
    u16* Bfc2 = (u16*)w; w += (size_t)CDIM*HID*2;
    u16* hA   = (u16*)w; w += (size_t)RPAD*CDIM*2;   // blob activations (768)
    u16* h3A  = (u16*)w; w += (size_t)RPAD*HID*2;    // blob activations (3072)
    u16* qkv_bf = (u16*)w; w += (size_t)RTOT*3*CDIM*2; // row-major
    u16* Qp   = (u16*)w; w += (size_t)BH*QT*1024*2;
    u16* Kp   = (u16*)w; w += (size_t)BH*QT*1024*2;
    u16* Vp   = (u16*)w; w += (size_t)BH*4*20*512*2;

    // 0. weights -> fragment blobs
    wconvert_blob<<<dim3(3*CDIM/256, CDIM/8), 256, 0, stream>>>(w_qkv,  Bqkv, CDIM, 3*CDIM);
    wconvert_blob<<<dim3(CDIM/256,   CDIM/8), 256, 0, stream>>>(w_proj, Bproj, CDIM, CDIM);
    wconvert_blob<<<dim3(HID/256,    CDIM/8), 256, 0, stream>>>(w_fc1,  Bfc1, CDIM, HID);
    wconvert_blob<<<dim3(CDIM/256,   HID/8),  256, 0, stream>>>(w_fc2,  Bfc2, HID, CDIM);

    // 1. hA = LN1(x)  (blob)
    ln_kernel<<<RTOT, 256, 0, stream>>>(x, ln1_g, ln1_b, hA);
    // 2. qkv = hA @ Bqkv^T + b_qkv  (row-major bf16 out)
    flat_gemm<<<dim3(3*CDIM/128, MT), 256, 0, stream>>>(
        hA, Bqkv, b_qkv, nullptr, qkv_bf, RTOT, 3*CDIM, CDIM, 2);
    // 3. attention blobs
    repack_qk<<<dim3(QT, BH, 2), 256, 0, stream>>>(qkv_bf, Qp, Kp);
    repack_v <<<dim3(10, BH),    256, 0, stream>>>(qkv_bf, Vp);
    // 4. attention -> hA (blob)
    attn_mfma<<<dim3(10, BH), 256, 0, stream>>>(Qp, Kp, Vp, hA);
    // 5. x1 = x + hA @ Bproj^T + b_proj -> d_out (fp32)
    flat_gemm<<<dim3(CDIM/128, MT), 256, 0, stream>>>(
        hA, Bproj, b_proj, x, out, RTOT, CDIM, CDIM, 0);
    // 6. hA = LN2(x1)  (blob)
    ln_kernel<<<RTOT, 256, 0, stream>>>(out, ln2_g, ln2_b, hA);
    // 7. h3A = gelu(hA @ Bfc1^T + b_fc1)  (blob out)
    flat_gemm<<<dim3(HID/128, MT), 256, 0, stream>>>(
        hA, Bfc1, b_fc1, nullptr, h3A, RTOT, HID, CDIM, 1 | 4);
    // 8. out = x1 + h3A @ Bfc2^T + b_fc2  (fp32, res==out same-thread)
    flat_gemm<<<dim3(CDIM/128, MT), 256, 0, stream>>>(
        h3A, Bfc2, b_fc2, out, out, RTOT, CDIM, HID, 0);
}

// Round 7
// 556.656 us; speedup vs baseline: 1.0290x; 1.0290x over previous
//
#include <hip/hip_runtime.h>
#include <hip/hip_bf16.h>
#include <math.h>

#define NB   16
#define NTOK 577
#define CDIM 768
#define NH   12
#define HID  3072
#define RTOT (NB*NTOK)        // 9232
#define MT64 ((RTOT+63)/64)   // 145 -> use 146 tiles of 64 on RPAD
#define RPAD (((RTOT+127)/128)*128) // 9344
#define BH   (NB*NH)          // 192
#define QT   40               // 640/16 fragment-tiles per (b,h)
#define KF_C (CDIM/32)        // 24

typedef __attribute__((ext_vector_type(8))) short bf16x8;
typedef __attribute__((ext_vector_type(4))) float f32x4;
typedef unsigned short u16;

__device__ inline void load_lds16(const void* g, void* l) {
    __builtin_amdgcn_global_load_lds(
        (const __attribute__((address_space(1))) unsigned*)g,
        (__attribute__((address_space(3))) unsigned*)l, 16, 0, 0);
}

// fragment-blob address for element (m, c) of an [M][C] bf16 matrix packed in
// MFMA A-operand order: blob(mt, kf) is 512 u16, lane(fq*16+fr) holds 8 elems.
__device__ inline size_t blobA(int m, int c, int Kf) {
    return ((size_t)(m >> 4) * Kf + (c >> 5)) * 512 +
           (((c >> 3) & 3) * 16 + (m & 15)) * 8 + (c & 7);
}

// exp-based tanh gelu
__device__ inline float fast_gelu(float x) {
    float y = 0.7978845608f * (x + 0.044715f * x * x * x);
    float e = __expf(2.0f * y);
    float th = 1.0f - 2.0f / (e + 1.0f);
    return 0.5f * x * (1.0f + th);
}

// ---------------------------------------------------------------------------
// Weight fp32 [K][N] -> bf16 fragment blobs (B-operand: roles m->n, c->k).
// ---------------------------------------------------------------------------
__global__ __launch_bounds__(256) void wconvert_blob(
    const float* __restrict__ src, u16* __restrict__ dst, int K, int N)
{
    int n  = blockIdx.x * 256 + threadIdx.x;
    int kp = blockIdx.y;                     // k-chunk of 8
    const float* s = src + (size_t)(kp * 8) * N + n;
    __hip_bfloat16 h0 = __float2bfloat16(s[0 * N]);
    __hip_bfloat16 h1 = __float2bfloat16(s[1 * N]);
    __hip_bfloat16 h2 = __float2bfloat16(s[2 * N]);
    __hip_bfloat16 h3 = __float2bfloat16(s[3 * N]);
    __hip_bfloat16 h4 = __float2bfloat16(s[4 * N]);
    __hip_bfloat16 h5 = __float2bfloat16(s[5 * N]);
    __hip_bfloat16 h6 = __float2bfloat16(s[6 * N]);
    __hip_bfloat16 h7 = __float2bfloat16(s[7 * N]);
    ushort4 a = make_ushort4(*(u16*)&h0, *(u16*)&h1, *(u16*)&h2, *(u16*)&h3);
    ushort4 b = make_ushort4(*(u16*)&h4, *(u16*)&h5, *(u16*)&h6, *(u16*)&h7);
    u16* d = dst + ((size_t)(n >> 4) * (K >> 5) + (kp >> 2)) * 512 +
             ((kp & 3) * 16 + (n & 15)) * 8;
    *(ushort4*)(d)     = a;
    *(ushort4*)(d + 4) = b;
}

// ---------------------------------------------------------------------------
// LayerNorm -> bf16 fragment blob (Kf = 24)
// ---------------------------------------------------------------------------
__global__ __launch_bounds__(256) void ln_kernel(
    const float* __restrict__ x, const float* __restrict__ g,
    const float* __restrict__ b, u16* __restrict__ out)
{
    int row = blockIdx.x;
    const float* xr = x + (size_t)row * CDIM;
    int t = threadIdx.x;
    float v0 = xr[t], v1 = xr[t + 256], v2 = xr[t + 512];
    float s  = v0 + v1 + v2;
    float s2 = v0*v0 + v1*v1 + v2*v2;
    #pragma unroll
    for (int off = 32; off; off >>= 1) {
        s  += __shfl_xor(s, off);
        s2 += __shfl_xor(s2, off);
    }
    __shared__ float red[10];
    int wave = t >> 6, lane = t & 63;
    if (lane == 0) { red[wave] = s; red[wave + 4] = s2; }
    __syncthreads();
    if (t == 0) {
        float ts  = red[0] + red[1] + red[2] + red[3];
        float ts2 = red[4] + red[5] + red[6] + red[7];
        float mu  = ts * (1.0f / CDIM);
        float var = ts2 * (1.0f / CDIM) - mu * mu;
        red[8] = mu;
        red[9] = rsqrtf(var + 1e-5f);
    }
    __syncthreads();
    float mu = red[8], rs = red[9];
    #pragma unroll
    for (int i = 0; i < 3; ++i) {
        int c = t + i * 256;
        float v = (i == 0 ? v0 : (i == 1 ? v1 : v2));
        __hip_bfloat16 hb = __float2bfloat16((v - mu) * rs * g[c] + b[c]);
        out[blobA(row, c, KF_C)] = *(u16*)&hb;
    }
}

// ---------------------------------------------------------------------------
// Barrier-free single-wave flatmm: 64-thread block computes a 64x64 tile.
// A, B in fragment-blob order; no LDS, no barriers; waves fully independent.
// flags: bit0=gelu, bit2=bf16 blob out, bit3=qkv scatter (Qp/Kp/Vp blobs).
// Default epilogue: fp32 out (+res).
// ---------------------------------------------------------------------------
__global__ __launch_bounds__(64) void flat_gemm(
    const u16* __restrict__ Ab, const u16* __restrict__ Bb,
    const float* __restrict__ bias, const float* __restrict__ res,
    void* __restrict__ outv,
    u16* __restrict__ Qp, u16* __restrict__ Kp, u16* __restrict__ Vp,
    int M, int Nc, int K, int flags)
{
    int lane = threadIdx.x & 63;
    int fr = lane & 15, fq = lane >> 4;
    int Kf = K >> 5;
    int m0 = blockIdx.y * 64, n0 = blockIdx.x * 64;

    size_t tstr = (size_t)Kf * 512;
    const u16* Ap = Ab + (size_t)(m0 >> 4) * tstr + lane * 8;
    const u16* Bp = Bb + (size_t)(n0 >> 4) * tstr + lane * 8;

    f32x4 acc[4][4];
    #pragma unroll
    for (int i = 0; i < 4; ++i)
        #pragma unroll
        for (int j = 0; j < 4; ++j) acc[i][j] = (f32x4){0.f, 0.f, 0.f, 0.f};

    bf16x8 af[4], bf[4];
    #pragma unroll
    for (int tm = 0; tm < 4; ++tm) af[tm] = *(const bf16x8*)(Ap + tm * tstr);
    #pragma unroll
    for (int tn = 0; tn < 4; ++tn) bf[tn] = *(const bf16x8*)(Bp + tn * tstr);

    for (int kf = 0; kf < Kf; ++kf) {
        bf16x8 an[4], bn[4];
        if (kf + 1 < Kf) {
            size_t o = (size_t)(kf + 1) * 512;
            #pragma unroll
            for (int tm = 0; tm < 4; ++tm)
                an[tm] = *(const bf16x8*)(Ap + tm * tstr + o);
            #pragma unroll
            for (int tn = 0; tn < 4; ++tn)
                bn[tn] = *(const bf16x8*)(Bp + tn * tstr + o);
        }
        #pragma unroll
        for (int tm = 0; tm < 4; ++tm)
            #pragma unroll
            for (int tn = 0; tn < 4; ++tn)
                acc[tm][tn] = __builtin_amdgcn_mfma_f32_16x16x32_bf16(
                    af[tm], bf[tn], acc[tm][tn], 0, 0, 0);
        #pragma unroll
        for (int i = 0; i < 4; ++i) { af[i] = an[i]; bf[i] = bn[i]; }
    }

    float* outf = (float*)outv;
    u16* outblob = (u16*)outv;
    int gelu = flags & 1;
    int KfO = Nc >> 5;

    if (flags & 8) {
        // qkv scatter: this 64-col tile is one (sec, head), uniform per block
        int sec = n0 / CDIM;
        int h   = (n0 % CDIM) / 64;
        #pragma unroll
        for (int tm = 0; tm < 4; ++tm) {
            #pragma unroll
            for (int rg = 0; rg < 4; ++rg) {
                int gm = m0 + tm * 16 + fq * 4 + rg;
                if (gm >= M) continue;
                int b   = gm / NTOK;
                int row = gm - b * NTOK;
                int bh  = b * NH + h;
                #pragma unroll
                for (int tn = 0; tn < 4; ++tn) {
                    int d = tn * 16 + fr;
                    float v = acc[tm][tn][rg] + bias[n0 + tn * 16 + fr];
                    __hip_bfloat16 hb = __float2bfloat16(v);
                    if (sec == 0) {
                        Qp[(size_t)(bh * QT + (row >> 4)) * 1024 + (d >> 5) * 512 +
                           (((d >> 3) & 3) * 16 + (row & 15)) * 8 + (d & 7)] = *(u16*)&hb;
                    } else if (sec == 1) {
                        Kp[(size_t)(bh * QT + (row >> 4)) * 1024 + (d >> 5) * 512 +
                           (((d >> 3) & 3) * 16 + (row & 15)) * 8 + (d & 7)] = *(u16*)&hb;
                    } else {
                        Vp[((size_t)(bh * 4 + (d >> 4)) * 20 + (row >> 5)) * 512 +
                           (((row >> 3) & 3) * 16 + (d & 15)) * 8 + (row & 7)] = *(u16*)&hb;
                    }
                }
            }
        }
        return;
    }

    #pragma unroll
    for (int tm = 0; tm < 4; ++tm) {
        #pragma unroll
        for (int rg = 0; rg < 4; ++rg) {
            int gm = m0 + tm * 16 + fq * 4 + rg;
            if (gm >= M) continue;
            #pragma unroll
            for (int tn = 0; tn < 4; ++tn) {
                int gn = n0 + tn * 16 + fr;
                float v = acc[tm][tn][rg] + bias[gn];
                if (gelu) v = fast_gelu(v);
                if (res)  v += res[(size_t)gm * Nc + gn];
                if (flags & 4) {
                    __hip_bfloat16 hb = __float2bfloat16(v);
                    outblob[blobA(gm, gn, KfO)] = *(u16*)&hb;
                } else {
                    outf[(size_t)gm * Nc + gn] = v;
                }
            }
        }
    }
}

// ---------------------------------------------------------------------------
// MFMA flash attention; output written in fragment-blob order (proj's A).
// ---------------------------------------------------------------------------
__global__ __launch_bounds__(256) void attn_mfma(
    const u16* __restrict__ Qp, const u16* __restrict__ Kp,
    const u16* __restrict__ Vp, u16* __restrict__ outp)
{
    __shared__ __align__(16) u16 Ks[4096];
    __shared__ __align__(16) u16 Vs[4096];
    __shared__ __align__(16) u16 Ps[4 * 16 * 72];

    int bh = blockIdx.y, qc = blockIdx.x;
    int b = bh / NH, h = bh % NH;
    int t = threadIdx.x, lane = t & 63, wv = t >> 6;
    int fr = lane & 15, fq = lane >> 4;

    int mt = qc * 4 + wv;
    const u16* qbase = Qp + (size_t)(bh * QT + mt) * 1024 + lane * 8;
    bf16x8 qf0 = *(const bf16x8*)(qbase);
    bf16x8 qf1 = *(const bf16x8*)(qbase + 512);

    const u16* kg = Kp + (size_t)bh * (QT * 1024) + wv * 1024 + lane * 8;
    const u16* vg = Vp + ((size_t)(bh * 4 + wv) * 20) * 512 + lane * 8;
    u16* lK  = Ks + wv * 1024;
    u16* lV  = Vs + wv * 1024;
    u16* psw = Ps + wv * (16 * 72);

    f32x4 o[4];
    float m_r[4], l_r[4];
    #pragma unroll
    for (int i = 0; i < 4; ++i) {
        o[i] = (f32x4){0.f, 0.f, 0.f, 0.f};
        m_r[i] = -1e30f; l_r[i] = 0.f;
    }

    for (int kt = 0; kt < 10; ++kt) {
        load_lds16(kg + kt * 4096,       lK);
        load_lds16(kg + kt * 4096 + 512, lK + 512);
        load_lds16(vg + kt * 1024,       lV);
        load_lds16(vg + kt * 1024 + 512, lV + 512);
        __syncthreads();

        f32x4 sc[4];
        #pragma unroll
        for (int nt = 0; nt < 4; ++nt) {
            sc[nt] = (f32x4){0.f, 0.f, 0.f, 0.f};
            bf16x8 kf0 = *(const bf16x8*)(Ks + (nt * 2 + 0) * 512 + lane * 8);
            bf16x8 kf1 = *(const bf16x8*)(Ks + (nt * 2 + 1) * 512 + lane * 8);
            sc[nt] = __builtin_amdgcn_mfma_f32_16x16x32_bf16(qf0, kf0, sc[nt], 0, 0, 0);
            sc[nt] = __builtin_amdgcn_mfma_f32_16x16x32_bf16(qf1, kf1, sc[nt], 0, 0, 0);
        }

        int j0 = kt * 64;
        float p[4][4], rm[4];
        #pragma unroll
        for (int rg = 0; rg < 4; ++rg) rm[rg] = -1e30f;
        #pragma unroll
        for (int nt = 0; nt < 4; ++nt) {
            bool valid = (j0 + nt * 16 + fr) < NTOK;
            #pragma unroll
            for (int rg = 0; rg < 4; ++rg) {
                float sv = valid ? sc[nt][rg] * 0.125f : -1e30f;
                p[nt][rg] = sv;
                rm[rg] = fmaxf(rm[rg], sv);
            }
        }
        #pragma unroll
        for (int rg = 0; rg < 4; ++rg) {
            #pragma unroll
            for (int off = 1; off < 16; off <<= 1)
                rm[rg] = fmaxf(rm[rg], __shfl_xor(rm[rg], off));
        }
        float alpha[4], rs[4];
        #pragma unroll
        for (int rg = 0; rg < 4; ++rg) {
            float mn = fmaxf(m_r[rg], rm[rg]);
            alpha[rg] = __expf(m_r[rg] - mn);
            m_r[rg] = mn;
            rs[rg] = 0.f;
        }
        #pragma unroll
        for (int nt = 0; nt < 4; ++nt)
            #pragma unroll
            for (int rg = 0; rg < 4; ++rg) {
                float pv = __expf(p[nt][rg] - m_r[rg]);
                p[nt][rg] = pv;
                rs[rg] += pv;
            }
        #pragma unroll
        for (int rg = 0; rg < 4; ++rg) {
            #pragma unroll
            for (int off = 1; off < 16; off <<= 1)
                rs[rg] += __shfl_xor(rs[rg], off);
            l_r[rg] = l_r[rg] * alpha[rg] + rs[rg];
        }

        #pragma unroll
        for (int nt = 0; nt < 4; ++nt)
            #pragma unroll
            for (int rg = 0; rg < 4; ++rg) {
                __hip_bfloat16 hb = __float2bfloat16(p[nt][rg]);
                psw[(fq * 4 + rg) * 72 + nt * 16 + fr] = *(u16*)&hb;
            }
        #pragma unroll
        for (int dt = 0; dt < 4; ++dt)
            #pragma unroll
            for (int rg = 0; rg < 4; ++rg)
                o[dt][rg] *= alpha[rg];

        bf16x8 pf0 = *(const bf16x8*)(psw + fr * 72 + fq * 8);
        bf16x8 pf1 = *(const bf16x8*)(psw + fr * 72 + 32 + fq * 8);
        #pragma unroll
        for (int dt = 0; dt < 4; ++dt) {
            bf16x8 bv0 = *(const bf16x8*)(Vs + (dt * 2 + 0) * 512 + lane * 8);
            bf16x8 bv1 = *(const bf16x8*)(Vs + (dt * 2 + 1) * 512 + lane * 8);
            o[dt] = __builtin_amdgcn_mfma_f32_16x16x32_bf16(pf0, bv0, o[dt], 0, 0, 0);
            o[dt] = __builtin_amdgcn_mfma_f32_16x16x32_bf16(pf1, bv1, o[dt], 0, 0, 0);
        }
        __syncthreads();
    }

    #pragma unroll
    for (int rg = 0; rg < 4; ++rg) {
        int row = qc * 64 + wv * 16 + fq * 4 + rg;
        if (row < NTOK) {
            float rl = 1.0f / l_r[rg];
            int grow = b * NTOK + row;
            #pragma unroll
            for (int dt = 0; dt < 4; ++dt) {
                __hip_bfloat16 hb = __float2bfloat16(o[dt][rg] * rl);
                outp[blobA(grow, h * 64 + dt * 16 + fr, KF_C)] = *(u16*)&hb;
            }
        }
    }
}

// ---------------------------------------------------------------------------
extern "C" void kernel_launch(void* const* d_in, const int* in_sizes, int n_in,
                              void* d_out, int out_size, void* d_ws, size_t ws_size,
                              hipStream_t stream)
{
    const float* x      = (const float*)d_in[0];
    const float* ln1_g  = (const float*)d_in[1];
    const float* ln1_b  = (const float*)d_in[2];
    const float* w_qkv  = (const float*)d_in[3];
    const float* b_qkv  = (const float*)d_in[4];
    const float* w_proj = (const float*)d_in[5];
    const float* b_proj = (const float*)d_in[6];
    const float* ln2_g  = (const float*)d_in[7];
    const float* ln2_b  = (const float*)d_in[8];
    const float* w_fc1  = (const float*)d_in[9];
    const float* b_fc1  = (const float*)d_in[10];
    const float* w_fc2  = (const float*)d_in[11];
    const float* b_fc2  = (const float*)d_in[12];
    float* out = (float*)d_out;

    char* w = (char*)d_ws;
    u16* Bqkv = (u16*)w; w += (size_t)3*CDIM*CDIM*2;
    u16* Bproj= (u16*)w; w += (size_t)CDIM*CDIM*2;
    u16* Bfc1 = (u16*)w; w += (size_t)HID*CDIM*2;
    u16* Bfc2 = (u16*)w; w += (size_t)CDIM*HID*2;
    u16* hA   = (u16*)w; w += (size_t)RPAD*CDIM*2;   // blob activations (768)
    u16* h3A  = (u16*)w; w += (size_t)RPAD*HID*2;    // blob activations (3072)
    u16* Qp   = (u16*)w; w += (size_t)BH*QT*1024*2;
    u16* Kp   = (u16*)w; w += (size_t)BH*QT*1024*2;
    u16* Vp   = (u16*)w; w += (size_t)BH*4*20*512*2;

    int mb = RPAD / 64;   // 146

    // 0. weights -> fragment blobs
    wconvert_blob<<<dim3(3*CDIM/256, CDIM/8), 256, 0, stream>>>(w_qkv,  Bqkv, CDIM, 3*CDIM);
    wconvert_blob<<<dim3(CDIM/256,   CDIM/8), 256, 0, stream>>>(w_proj, Bproj, CDIM, CDIM);
    wconvert_blob<<<dim3(HID/256,    CDIM/8), 256, 0, stream>>>(w_fc1,  Bfc1, CDIM, HID);
    wconvert_blob<<<dim3(CDIM/256,   HID/8),  256, 0, stream>>>(w_fc2,  Bfc2, HID, CDIM);

    // 1. hA = LN1(x)  (blob)
    ln_kernel<<<RTOT, 256, 0, stream>>>(x, ln1_g, ln1_b, hA);
    // 2. qkv GEMM, epilogue scatters straight into Q/K/V attention blobs
    flat_gemm<<<dim3(3*CDIM/64, mb), 64, 0, stream>>>(
        hA, Bqkv, b_qkv, nullptr, nullptr, Qp, Kp, Vp, RTOT, 3*CDIM, CDIM, 8);
    // 3. attention -> hA (blob)
    attn_mfma<<<dim3(10, BH), 256, 0, stream>>>(Qp, Kp, Vp, hA);
    // 4. x1 = x + hA @ Bproj^T + b_proj -> d_out (fp32)
    flat_gemm<<<dim3(CDIM/64, mb), 64, 0, stream>>>(
        hA, Bproj, b_proj, x, out, nullptr, nullptr, nullptr, RTOT, CDIM, CDIM, 0);
    // 5. hA = LN2(x1)  (blob)
    ln_kernel<<<RTOT, 256, 0, stream>>>(out, ln2_g, ln2_b, hA);
    // 6. h3A = gelu(hA @ Bfc1^T + b_fc1)  (blob out)
    flat_gemm<<<dim3(HID/64, mb), 64, 0, stream>>>(
        hA, Bfc1, b_fc1, nullptr, h3A, nullptr, nullptr, nullptr, RTOT, HID, CDIM, 1 | 4);
    // 7. out = x1 + h3A @ Bfc2^T + b_fc2  (fp32, res==out same-thread)
    flat_gemm<<<dim3(CDIM/64, mb), 64, 0, stream>>>(
        h3A, Bfc2, b_fc2, out, out, nullptr, nullptr, nullptr, RTOT, CDIM, HID, 0);
}

// Round 8
// 488.936 us; speedup vs baseline: 1.1715x; 1.1385x over previous
//
#include <hip/hip_runtime.h>
#include <hip/hip_bf16.h>
#include <math.h>

#define NB   16
#define NTOK 577
#define CDIM 768
#define NH   12
#define HID  3072
#define RTOT (NB*NTOK)        // 9232
#define RPAD (((RTOT+127)/128)*128) // 9344
#define BH   (NB*NH)          // 192
#define QT   40               // 640/16 fragment-tiles per (b,h)
#define KF_C (CDIM/32)        // 24

typedef __attribute__((ext_vector_type(8))) short bf16x8;
typedef __attribute__((ext_vector_type(4))) float f32x4;
typedef unsigned short u16;

__device__ inline void load_lds16(const void* g, void* l) {
    __builtin_amdgcn_global_load_lds(
        (const __attribute__((address_space(1))) unsigned*)g,
        (__attribute__((address_space(3))) unsigned*)l, 16, 0, 0);
}

// fragment-blob address for element (m, c) of an [M][C] bf16 matrix packed in
// MFMA A-operand order: blob(mt, kf) is 512 u16, lane(fq*16+fr) holds 8 elems.
__device__ inline size_t blobA(int m, int c, int Kf) {
    return ((size_t)(m >> 4) * Kf + (c >> 5)) * 512 +
           (((c >> 3) & 3) * 16 + (m & 15)) * 8 + (c & 7);
}

// exp-based tanh gelu
__device__ inline float fast_gelu(float x) {
    float y = 0.7978845608f * (x + 0.044715f * x * x * x);
    float e = __expf(2.0f * y);
    float th = 1.0f - 2.0f / (e + 1.0f);
    return 0.5f * x * (1.0f + th);
}

// ---------------------------------------------------------------------------
// Weight fp32 [K][N] -> bf16 fragment blobs (B-operand: roles m->n, c->k).
// ---------------------------------------------------------------------------
__global__ __launch_bounds__(256) void wconvert_blob(
    const float* __restrict__ src, u16* __restrict__ dst, int K, int N)
{
    int n  = blockIdx.x * 256 + threadIdx.x;
    int kp = blockIdx.y;                     // k-chunk of 8
    const float* s = src + (size_t)(kp * 8) * N + n;
    __hip_bfloat16 h0 = __float2bfloat16(s[0 * N]);
    __hip_bfloat16 h1 = __float2bfloat16(s[1 * N]);
    __hip_bfloat16 h2 = __float2bfloat16(s[2 * N]);
    __hip_bfloat16 h3 = __float2bfloat16(s[3 * N]);
    __hip_bfloat16 h4 = __float2bfloat16(s[4 * N]);
    __hip_bfloat16 h5 = __float2bfloat16(s[5 * N]);
    __hip_bfloat16 h6 = __float2bfloat16(s[6 * N]);
    __hip_bfloat16 h7 = __float2bfloat16(s[7 * N]);
    ushort4 a = make_ushort4(*(u16*)&h0, *(u16*)&h1, *(u16*)&h2, *(u16*)&h3);
    ushort4 b = make_ushort4(*(u16*)&h4, *(u16*)&h5, *(u16*)&h6, *(u16*)&h7);
    u16* d = dst + ((size_t)(n >> 4) * (K >> 5) + (kp >> 2)) * 512 +
             ((kp & 3) * 16 + (n & 15)) * 8;
    *(ushort4*)(d)     = a;
    *(ushort4*)(d + 4) = b;
}

// ---------------------------------------------------------------------------
// LayerNorm -> bf16 fragment blob (Kf = 24)
// ---------------------------------------------------------------------------
__global__ __launch_bounds__(256) void ln_kernel(
    const float* __restrict__ x, const float* __restrict__ g,
    const float* __restrict__ b, u16* __restrict__ out)
{
    int row = blockIdx.x;
    const float* xr = x + (size_t)row * CDIM;
    int t = threadIdx.x;
    float v0 = xr[t], v1 = xr[t + 256], v2 = xr[t + 512];
    float s  = v0 + v1 + v2;
    float s2 = v0*v0 + v1*v1 + v2*v2;
    #pragma unroll
    for (int off = 32; off; off >>= 1) {
        s  += __shfl_xor(s, off);
        s2 += __shfl_xor(s2, off);
    }
    __shared__ float red[10];
    int wave = t >> 6, lane = t & 63;
    if (lane == 0) { red[wave] = s; red[wave + 4] = s2; }
    __syncthreads();
    if (t == 0) {
        float ts  = red[0] + red[1] + red[2] + red[3];
        float ts2 = red[4] + red[5] + red[6] + red[7];
        float mu  = ts * (1.0f / CDIM);
        float var = ts2 * (1.0f / CDIM) - mu * mu;
        red[8] = mu;
        red[9] = rsqrtf(var + 1e-5f);
    }
    __syncthreads();
    float mu = red[8], rs = red[9];
    #pragma unroll
    for (int i = 0; i < 3; ++i) {
        int c = t + i * 256;
        float v = (i == 0 ? v0 : (i == 1 ? v1 : v2));
        __hip_bfloat16 hb = __float2bfloat16((v - mu) * rs * g[c] + b[c]);
        out[blobA(row, c, KF_C)] = *(u16*)&hb;
    }
}

// ---------------------------------------------------------------------------
// Barrier-free single-wave flatmm. Wave tile = (TM*16) x 64. 1-D grid with
// XCD swizzle: fid&7 picks the m-slab residue so one XCD's L2 owns a slab's
// A tiles while its n-blocks sweep. flags: bit0=gelu, bit2=blob out (LDS-
// coalesced), bit3=qkv scatter. Default: fp32 out (+res).
// ---------------------------------------------------------------------------
template<int TM>
__global__ __launch_bounds__(64) void flat_gemm(
    const u16* __restrict__ Ab, const u16* __restrict__ Bb,
    const float* __restrict__ bias, const float* __restrict__ res,
    void* __restrict__ outv,
    u16* __restrict__ Qp, u16* __restrict__ Kp, u16* __restrict__ Vp,
    int M, int Nc, int K, int nb, int mb, int flags)
{
    __shared__ u16 sb[TM * 1024];   // blob-epilogue staging (wave-sync)
    int lane = threadIdx.x & 63;
    int fr = lane & 15, fq = lane >> 4;

    int fid = blockIdx.x;
    int xcd = fid & 7, w = fid >> 3;
    int slab = w / nb, n = w - slab * nb;
    int m = slab * 8 + xcd;
    if (m >= mb) return;
    int m0 = m * (TM * 16), n0 = n * 64;

    int Kf = K >> 5;
    size_t tstr = (size_t)Kf * 512;
    const u16* Ap = Ab + (size_t)(m0 >> 4) * tstr + lane * 8;
    const u16* Bp = Bb + (size_t)(n0 >> 4) * tstr + lane * 8;

    f32x4 acc[TM][4];
    #pragma unroll
    for (int i = 0; i < TM; ++i)
        #pragma unroll
        for (int j = 0; j < 4; ++j) acc[i][j] = (f32x4){0.f, 0.f, 0.f, 0.f};

    bf16x8 af[TM], bf[4];
    #pragma unroll
    for (int tm = 0; tm < TM; ++tm) af[tm] = *(const bf16x8*)(Ap + tm * tstr);
    #pragma unroll
    for (int tn = 0; tn < 4; ++tn) bf[tn] = *(const bf16x8*)(Bp + tn * tstr);

    for (int kf = 0; kf < Kf; ++kf) {
        bf16x8 an[TM], bn[4];
        if (kf + 1 < Kf) {
            size_t o = (size_t)(kf + 1) * 512;
            #pragma unroll
            for (int tm = 0; tm < TM; ++tm)
                an[tm] = *(const bf16x8*)(Ap + tm * tstr + o);
            #pragma unroll
            for (int tn = 0; tn < 4; ++tn)
                bn[tn] = *(const bf16x8*)(Bp + tn * tstr + o);
        }
        #pragma unroll
        for (int tm = 0; tm < TM; ++tm)
            #pragma unroll
            for (int tn = 0; tn < 4; ++tn)
                acc[tm][tn] = __builtin_amdgcn_mfma_f32_16x16x32_bf16(
                    af[tm], bf[tn], acc[tm][tn], 0, 0, 0);
        #pragma unroll
        for (int i = 0; i < TM; ++i) af[i] = an[i];
        #pragma unroll
        for (int i = 0; i < 4; ++i)  bf[i] = bn[i];
    }

    float* outf = (float*)outv;
    u16* outblob = (u16*)outv;
    int gelu = flags & 1;
    int KfO = Nc >> 5;

    if (flags & 8) {
        // qkv scatter: 64-col tile is one (sec, head), uniform per block
        int sec = n0 / CDIM;
        int h   = (n0 % CDIM) / 64;
        #pragma unroll
        for (int tm = 0; tm < TM; ++tm) {
            #pragma unroll
            for (int rg = 0; rg < 4; ++rg) {
                int gm = m0 + tm * 16 + fq * 4 + rg;
                if (gm >= M) continue;
                int b   = gm / NTOK;
                int row = gm - b * NTOK;
                int bh  = b * NH + h;
                #pragma unroll
                for (int tn = 0; tn < 4; ++tn) {
                    int d = tn * 16 + fr;
                    float v = acc[tm][tn][rg] + bias[n0 + tn * 16 + fr];
                    __hip_bfloat16 hb = __float2bfloat16(v);
                    if (sec == 0) {
                        Qp[(size_t)(bh * QT + (row >> 4)) * 1024 + (d >> 5) * 512 +
                           (((d >> 3) & 3) * 16 + (row & 15)) * 8 + (d & 7)] = *(u16*)&hb;
                    } else if (sec == 1) {
                        Kp[(size_t)(bh * QT + (row >> 4)) * 1024 + (d >> 5) * 512 +
                           (((d >> 3) & 3) * 16 + (row & 15)) * 8 + (d & 7)] = *(u16*)&hb;
                    } else {
                        Vp[((size_t)(bh * 4 + (d >> 4)) * 20 + (row >> 5)) * 512 +
                           (((row >> 3) & 3) * 16 + (d & 15)) * 8 + (row & 7)] = *(u16*)&hb;
                    }
                }
            }
        }
        return;
    }

    if (flags & 4) {
        // blob out: stage TM 16x64 sub-tiles (1 KB each, contiguous in blob
        // space) in LDS, then coalesced 16B stores. Wave-synchronous: single
        // wave, program order preserves ds_write -> ds_read.
        #pragma unroll
        for (int tm = 0; tm < TM; ++tm)
            #pragma unroll
            for (int tn = 0; tn < 4; ++tn)
                #pragma unroll
                for (int rg = 0; rg < 4; ++rg) {
                    int cl = tn * 16 + fr;
                    float v = acc[tm][tn][rg] + bias[n0 + cl];
                    if (gelu) v = fast_gelu(v);
                    __hip_bfloat16 hb = __float2bfloat16(v);
                    sb[tm * 1024 + (cl >> 5) * 512 +
                       (((cl >> 3) & 3) * 16 + fq * 4 + rg) * 8 + (cl & 7)] = *(u16*)&hb;
                }
        #pragma unroll
        for (int tm = 0; tm < TM; ++tm) {
            u16* dst = outblob + ((size_t)((m0 >> 4) + tm) * KfO + (n0 >> 5)) * 512;
            *(bf16x8*)(dst + lane * 16)     = *(const bf16x8*)(sb + tm * 1024 + lane * 16);
            *(bf16x8*)(dst + lane * 16 + 8) = *(const bf16x8*)(sb + tm * 1024 + lane * 16 + 8);
        }
        return;
    }

    #pragma unroll
    for (int tm = 0; tm < TM; ++tm) {
        #pragma unroll
        for (int rg = 0; rg < 4; ++rg) {
            int gm = m0 + tm * 16 + fq * 4 + rg;
            if (gm >= M) continue;
            #pragma unroll
            for (int tn = 0; tn < 4; ++tn) {
                int gn = n0 + tn * 16 + fr;
                float v = acc[tm][tn][rg] + bias[gn];
                if (gelu) v = fast_gelu(v);
                if (res)  v += res[(size_t)gm * Nc + gn];
                outf[(size_t)gm * Nc + gn] = v;
            }
        }
    }
}

// ---------------------------------------------------------------------------
// MFMA flash attention; output written in fragment-blob order (proj's A).
// ---------------------------------------------------------------------------
__global__ __launch_bounds__(256) void attn_mfma(
    const u16* __restrict__ Qp, const u16* __restrict__ Kp,
    const u16* __restrict__ Vp, u16* __restrict__ outp)
{
    __shared__ __align__(16) u16 Ks[4096];
    __shared__ __align__(16) u16 Vs[4096];
    __shared__ __align__(16) u16 Ps[4 * 16 * 72];

    int bh = blockIdx.y, qc = blockIdx.x;
    int b = bh / NH, h = bh % NH;
    int t = threadIdx.x, lane = t & 63, wv = t >> 6;
    int fr = lane & 15, fq = lane >> 4;

    int mt = qc * 4 + wv;
    const u16* qbase = Qp + (size_t)(bh * QT + mt) * 1024 + lane * 8;
    bf16x8 qf0 = *(const bf16x8*)(qbase);
    bf16x8 qf1 = *(const bf16x8*)(qbase + 512);

    const u16* kg = Kp + (size_t)bh * (QT * 1024) + wv * 1024 + lane * 8;
    const u16* vg = Vp + ((size_t)(bh * 4 + wv) * 20) * 512 + lane * 8;
    u16* lK  = Ks + wv * 1024;
    u16* lV  = Vs + wv * 1024;
    u16* psw = Ps + wv * (16 * 72);

    f32x4 o[4];
    float m_r[4], l_r[4];
    #pragma unroll
    for (int i = 0; i < 4; ++i) {
        o[i] = (f32x4){0.f, 0.f, 0.f, 0.f};
        m_r[i] = -1e30f; l_r[i] = 0.f;
    }

    for (int kt = 0; kt < 10; ++kt) {
        load_lds16(kg + kt * 4096,       lK);
        load_lds16(kg + kt * 4096 + 512, lK + 512);
        load_lds16(vg + kt * 1024,       lV);
        load_lds16(vg + kt * 1024 + 512, lV + 512);
        __syncthreads();

        f32x4 sc[4];
        #pragma unroll
        for (int nt = 0; nt < 4; ++nt) {
            sc[nt] = (f32x4){0.f, 0.f, 0.f, 0.f};
            bf16x8 kf0 = *(const bf16x8*)(Ks + (nt * 2 + 0) * 512 + lane * 8);
            bf16x8 kf1 = *(const bf16x8*)(Ks + (nt * 2 + 1) * 512 + lane * 8);
            sc[nt] = __builtin_amdgcn_mfma_f32_16x16x32_bf16(qf0, kf0, sc[nt], 0, 0, 0);
            sc[nt] = __builtin_amdgcn_mfma_f32_16x16x32_bf16(qf1, kf1, sc[nt], 0, 0, 0);
        }

        int j0 = kt * 64;
        float p[4][4], rm[4];
        #pragma unroll
        for (int rg = 0; rg < 4; ++rg) rm[rg] = -1e30f;
        #pragma unroll
        for (int nt = 0; nt < 4; ++nt) {
            bool valid = (j0 + nt * 16 + fr) < NTOK;
            #pragma unroll
            for (int rg = 0; rg < 4; ++rg) {
                float sv = valid ? sc[nt][rg] * 0.125f : -1e30f;
                p[nt][rg] = sv;
                rm[rg] = fmaxf(rm[rg], sv);
            }
        }
        #pragma unroll
        for (int rg = 0; rg < 4; ++rg) {
            #pragma unroll
            for (int off = 1; off < 16; off <<= 1)
                rm[rg] = fmaxf(rm[rg], __shfl_xor(rm[rg], off));
        }
        float alpha[4], rs[4];
        #pragma unroll
        for (int rg = 0; rg < 4; ++rg) {
            float mn = fmaxf(m_r[rg], rm[rg]);
            alpha[rg] = __expf(m_r[rg] - mn);
            m_r[rg] = mn;
            rs[rg] = 0.f;
        }
        #pragma unroll
        for (int nt = 0; nt < 4; ++nt)
            #pragma unroll
            for (int rg = 0; rg < 4; ++rg) {
                float pv = __expf(p[nt][rg] - m_r[rg]);
                p[nt][rg] = pv;
                rs[rg] += pv;
            }
        #pragma unroll
        for (int rg = 0; rg < 4; ++rg) {
            #pragma unroll
            for (int off = 1; off < 16; off <<= 1)
                rs[rg] += __shfl_xor(rs[rg], off);
            l_r[rg] = l_r[rg] * alpha[rg] + rs[rg];
        }

        #pragma unroll
        for (int nt = 0; nt < 4; ++nt)
            #pragma unroll
            for (int rg = 0; rg < 4; ++rg) {
                __hip_bfloat16 hb = __float2bfloat16(p[nt][rg]);
                psw[(fq * 4 + rg) * 72 + nt * 16 + fr] = *(u16*)&hb;
            }
        #pragma unroll
        for (int dt = 0; dt < 4; ++dt)
            #pragma unroll
            for (int rg = 0; rg < 4; ++rg)
                o[dt][rg] *= alpha[rg];

        bf16x8 pf0 = *(const bf16x8*)(psw + fr * 72 + fq * 8);
        bf16x8 pf1 = *(const bf16x8*)(psw + fr * 72 + 32 + fq * 8);
        #pragma unroll
        for (int dt = 0; dt < 4; ++dt) {
            bf16x8 bv0 = *(const bf16x8*)(Vs + (dt * 2 + 0) * 512 + lane * 8);
            bf16x8 bv1 = *(const bf16x8*)(Vs + (dt * 2 + 1) * 512 + lane * 8);
            o[dt] = __builtin_amdgcn_mfma_f32_16x16x32_bf16(pf0, bv0, o[dt], 0, 0, 0);
            o[dt] = __builtin_amdgcn_mfma_f32_16x16x32_bf16(pf1, bv1, o[dt], 0, 0, 0);
        }
        __syncthreads();
    }

    #pragma unroll
    for (int rg = 0; rg < 4; ++rg) {
        int row = qc * 64 + wv * 16 + fq * 4 + rg;
        if (row < NTOK) {
            float rl = 1.0f / l_r[rg];
            int grow = b * NTOK + row;
            #pragma unroll
            for (int dt = 0; dt < 4; ++dt) {
                __hip_bfloat16 hb = __float2bfloat16(o[dt][rg] * rl);
                outp[blobA(grow, h * 64 + dt * 16 + fr, KF_C)] = *(u16*)&hb;
            }
        }
    }
}

// ---------------------------------------------------------------------------
static inline int swz_grid(int nb, int mb) { return nb * (((mb + 7) / 8) * 8); }

extern "C" void kernel_launch(void* const* d_in, const int* in_sizes, int n_in,
                              void* d_out, int out_size, void* d_ws, size_t ws_size,
                              hipStream_t stream)
{
    const float* x      = (const float*)d_in[0];
    const float* ln1_g  = (const float*)d_in[1];
    const float* ln1_b  = (const float*)d_in[2];
    const float* w_qkv  = (const float*)d_in[3];
    const float* b_qkv  = (const float*)d_in[4];
    const float* w_proj = (const float*)d_in[5];
    const float* b_proj = (const float*)d_in[6];
    const float* ln2_g  = (const float*)d_in[7];
    const float* ln2_b  = (const float*)d_in[8];
    const float* w_fc1  = (const float*)d_in[9];
    const float* b_fc1  = (const float*)d_in[10];
    const float* w_fc2  = (const float*)d_in[11];
    const float* b_fc2  = (const float*)d_in[12];
    float* out = (float*)d_out;

    char* w = (char*)d_ws;
    u16* Bqkv = (u16*)w; w += (size_t)3*CDIM*CDIM*2;
    u16* Bproj= (u16*)w; w += (size_t)CDIM*CDIM*2;
    u16* Bfc1 = (u16*)w; w += (size_t)HID*CDIM*2;
    u16* Bfc2 = (u16*)w; w += (size_t)CDIM*HID*2;
    u16* hA   = (u16*)w; w += (size_t)RPAD*CDIM*2;   // blob activations (768)
    u16* h3A  = (u16*)w; w += (size_t)RPAD*HID*2;    // blob activations (3072)
    u16* Qp   = (u16*)w; w += (size_t)BH*QT*1024*2;
    u16* Kp   = (u16*)w; w += (size_t)BH*QT*1024*2;
    u16* Vp   = (u16*)w; w += (size_t)BH*4*20*512*2;

    int mb4 = (RTOT + 63) / 64;    // 145 m-tiles for TM=4
    int mb2 = (RTOT + 31) / 32;    // 289 m-tiles for TM=2

    // 0. weights -> fragment blobs
    wconvert_blob<<<dim3(3*CDIM/256, CDIM/8), 256, 0, stream>>>(w_qkv,  Bqkv, CDIM, 3*CDIM);
    wconvert_blob<<<dim3(CDIM/256,   CDIM/8), 256, 0, stream>>>(w_proj, Bproj, CDIM, CDIM);
    wconvert_blob<<<dim3(HID/256,    CDIM/8), 256, 0, stream>>>(w_fc1,  Bfc1, CDIM, HID);
    wconvert_blob<<<dim3(CDIM/256,   HID/8),  256, 0, stream>>>(w_fc2,  Bfc2, HID, CDIM);

    // 1. hA = LN1(x)  (blob)
    ln_kernel<<<RTOT, 256, 0, stream>>>(x, ln1_g, ln1_b, hA);
    // 2. qkv GEMM, epilogue scatters straight into Q/K/V attention blobs
    flat_gemm<4><<<swz_grid(3*CDIM/64, mb4), 64, 0, stream>>>(
        hA, Bqkv, b_qkv, nullptr, nullptr, Qp, Kp, Vp,
        RTOT, 3*CDIM, CDIM, 3*CDIM/64, mb4, 8);
    // 3. attention -> hA (blob)
    attn_mfma<<<dim3(10, BH), 256, 0, stream>>>(Qp, Kp, Vp, hA);
    // 4. x1 = x + hA @ Bproj^T + b_proj -> d_out (fp32)
    flat_gemm<2><<<swz_grid(CDIM/64, mb2), 64, 0, stream>>>(
        hA, Bproj, b_proj, x, out, nullptr, nullptr, nullptr,
        RTOT, CDIM, CDIM, CDIM/64, mb2, 0);
    // 5. hA = LN2(x1)  (blob)
    ln_kernel<<<RTOT, 256, 0, stream>>>(out, ln2_g, ln2_b, hA);
    // 6. h3A = gelu(hA @ Bfc1^T + b_fc1)  (blob out, LDS-coalesced epilogue)
    flat_gemm<4><<<swz_grid(HID/64, mb4), 64, 0, stream>>>(
        hA, Bfc1, b_fc1, nullptr, h3A, nullptr, nullptr, nullptr,
        RTOT, HID, CDIM, HID/64, mb4, 1 | 4);
    // 7. out = x1 + h3A @ Bfc2^T + b_fc2  (fp32, res==out same-thread)
    flat_gemm<2><<<swz_grid(CDIM/64, mb2), 64, 0, stream>>>(
        h3A, Bfc2, b_fc2, out, out, nullptr, nullptr, nullptr,
        RTOT, CDIM, HID, CDIM/64, mb2, 0);
}